// Round 6
// baseline (4251.886 us; speedup 1.0000x reference)
//
#include <hip/hip_runtime.h>
#include <hip/hip_bf16.h>
#include <hip/hip_fp16.h>

#define B 256
#define L 128
#define F 256
#define S 512
#define G4 1024  // 4*F gate rows

typedef _Float16 h2raw __attribute__((ext_vector_type(2)));
typedef _Float16 f16x8 __attribute__((ext_vector_type(8)));
typedef float f32x4 __attribute__((ext_vector_type(4)));

__device__ __forceinline__ float fdot2u(unsigned a, unsigned b, float c) {
#if __has_builtin(__builtin_amdgcn_fdot2)
    return __builtin_amdgcn_fdot2(__builtin_bit_cast(h2raw, a), __builtin_bit_cast(h2raw, b), c, false);
#else
    __half2 ah = __builtin_bit_cast(__half2, a), bh = __builtin_bit_cast(__half2, b);
    float2 af = __half22float2(ah), bf = __half22float2(bh);
    return c + af.x * bf.x + af.y * bf.y;
#endif
}

// fast device transcendentals: v_exp_f32 / v_rcp_f32 based
__device__ __forceinline__ float fast_rcp(float x) { return __builtin_amdgcn_rcpf(x); }
__device__ __forceinline__ float sigf(float x) {
    float e = __expf(-x);
    return fast_rcp(1.0f + e);
}
__device__ __forceinline__ float tanhf_fast(float x) {
    x = fminf(fmaxf(x, -15.0f), 15.0f);
    float e = __expf(-2.0f * x);
    return (1.0f - e) * fast_rcp(1.0f + e);
}

template <int CTRL>
__device__ __forceinline__ float dpp_add(float x) {
    int v = __builtin_amdgcn_update_dpp(0, __builtin_bit_cast(int, x), CTRL, 0xF, 0xF, true);
    return x + __builtin_bit_cast(float, v);
}

// hbuf pair index -> padded dword index.
// Pairs [0,64) (k<128, MFMA B-frag region): contiguous dwords 0..63.
// Pairs [64,128) (k>=128, VALU region): 16-pair groups padded to 20 dwords so
// the four per-quarter b128 read groups hit disjoint banks AND stay 16B-aligned.
__device__ __forceinline__ int hidx(int p) {
    return (p < 64) ? p : 64 + ((p - 64) >> 4) * 20 + ((p - 64) & 15);
}

// Prep v8: two packings of combined W = W_ih + W_hh (fp16).
//  (1) MFMA A-frags for k in [0,128): frag f = T*4 + kf (row-tile T in [0,64),
//      k-frag kf in [0,4)); lane l, reg r: row = T*16 + (l&15),
//      k = kf*32 + (l>>4)*8 + 2r + {0,1}.  (R4-verified convention.)
//  (2) VALU pack for k in [128,256): chunk n = g*4 + m, thread t2 (j=t2>>2,
//      q=t2&3): 4 half2 = k-pairs kp = 64 + q*16 + m*4 + {0..3} of row g*256+j.
__global__ void prep_kernel(const float* __restrict__ Wih,
                            const float* __restrict__ Whh,
                            const float* __restrict__ bih,
                            const float* __restrict__ bhh,
                            uint4* __restrict__ WpkA, uint4* __restrict__ WpkV,
                            float* __restrict__ bias_sum) {
    int e = blockIdx.x * blockDim.x + threadIdx.x;  // 32768 elements
    if (e < G4) bias_sum[e] = bih[e] + bhh[e];
    if (e < 16384) {
        int f = e >> 6, l = e & 63;
        int T = f >> 2, kf = f & 3;
        int row = T * 16 + (l & 15);
        int k0 = kf * 32 + ((l >> 4) & 3) * 8;
        unsigned pk[4];
        #pragma unroll
        for (int r = 0; r < 4; ++r) {
            int k = k0 + 2 * r;
            float w0 = Wih[(size_t)row * F + k]     + Whh[(size_t)row * F + k];
            float w1 = Wih[(size_t)row * F + k + 1] + Whh[(size_t)row * F + k + 1];
            pk[r] = __builtin_bit_cast(unsigned, __floats2half2_rn(w0, w1));
        }
        WpkA[e] = make_uint4(pk[0], pk[1], pk[2], pk[3]);
    } else {
        int e2 = e - 16384;
        int n = e2 >> 10, t2 = e2 & 1023;
        int j = t2 >> 2, q = t2 & 3;
        int g = n >> 2, m = n & 3;
        int row = g * F + j;
        int kp0 = 64 + q * 16 + m * 4;
        unsigned pk[4];
        #pragma unroll
        for (int i = 0; i < 4; ++i) {
            int k = 2 * (kp0 + i);
            float w0 = Wih[(size_t)row * F + k]     + Whh[(size_t)row * F + k];
            float w1 = Wih[(size_t)row * F + k + 1] + Whh[(size_t)row * F + k + 1];
            pk[i] = __builtin_bit_cast(unsigned, __floats2half2_rn(w0, w1));
        }
        WpkV[(size_t)n * 1024 + t2] = make_uint4(pk[0], pk[1], pk[2], pk[3]);
    }
}

// init = elu(x[0] @ Wi.T + bi) -> h0, c0 (fp32 in workspace), float4 loads
__global__ void init_kernel(const float* __restrict__ x,
                            const float* __restrict__ Wi,
                            const float* __restrict__ bi,
                            float* __restrict__ h, float* __restrict__ c) {
    __shared__ float4 xs4[L / 4];
    int b = blockIdx.x, j = threadIdx.x;
    if (j < L / 4) xs4[j] = ((const float4*)(x + (size_t)b * L))[j];
    __syncthreads();
    float acc = bi[j];
    const float4* wp = (const float4*)(Wi + (size_t)j * L);
    #pragma unroll 8
    for (int k = 0; k < L / 4; ++k) {
        float4 w = wp[k], xv = xs4[k];
        acc += w.x * xv.x + w.y * xv.y + w.z * xv.z + w.w * xv.w;
    }
    float v = acc > 0.0f ? acc : expm1f(acc);
    h[b * F + j] = v;
    c[b * F + j] = v;
}

// Step 0: gates = last_feat @ W_ih.T + h0 @ W_hh.T + bias (fp32 exact path).
__global__ void step0_kernel(const float* __restrict__ lf,
                             const float* __restrict__ Wih,
                             const float* __restrict__ Whh,
                             const float* __restrict__ bias_sum,
                             float* __restrict__ h, float* __restrict__ c,
                             float* __restrict__ out) {
    __shared__ float vecs[2 * F];            // [inp(256) ; h0(256)]
    __shared__ float partial[3][4][F];
    int b = blockIdx.x, tid = threadIdx.x;
    int j = tid & (F - 1), q = tid >> 8;
    if (q == 0) vecs[j] = lf[(size_t)b * F + j];
    else if (q == 1) vecs[F + j] = h[(size_t)b * F + j];
    __syncthreads();
    const float* mat = (q < 2) ? Wih : Whh;
    int ks = (q & 1) * 128;
    const float4* vp = (const float4*)(&vecs[(q >> 1) * F + ks]);
    float a[4] = {0.f, 0.f, 0.f, 0.f};
    #pragma unroll
    for (int g = 0; g < 4; ++g) {
        const float4* wp = (const float4*)(&mat[(size_t)(g * F + j) * F + ks]);
        float acc = 0.f;
        #pragma unroll 8
        for (int i = 0; i < 32; ++i) {
            float4 w = wp[i], v = vp[i];
            acc += w.x * v.x + w.y * v.y + w.z * v.z + w.w * v.w;
        }
        a[g] = acc;
    }
    if (q > 0) {
        #pragma unroll
        for (int g = 0; g < 4; ++g) partial[q - 1][g][j] = a[g];
    }
    __syncthreads();
    if (q == 0) {
        #pragma unroll
        for (int g = 0; g < 4; ++g) {
            for (int p = 0; p < 3; ++p) a[g] += partial[p][g][j];
            a[g] += bias_sum[g * F + j];
        }
        float c0v = c[(size_t)b * F + j];
        float c1v = sigf(a[1]) * c0v + sigf(a[0]) * tanhf_fast(a[2]);
        float h1v = sigf(a[3]) * tanhf_fast(c1v);
        h[(size_t)b * F + j] = h1v;
        c[(size_t)b * F + j] = c1v;
        out[(size_t)b * F + j] = h1v;  // t=0 row
    }
}

// Main recurrence v8: HYBRID dual-pipe. 1024 threads (16 waves), 1 block/CU.
// Model (fits R0-R5): v_dot2_f32_f16 is HALF-RATE (4cy/wave) on gfx950, and
// the old gate-o LDS stream + h reads saturated the LDS pipe (256 wave-b128 x
// 12cy = 3072 cy/CU/step). Fix: split K between the two idle-complementary
// pipes and hold ALL weights in registers (budget at 4 waves/SIMD = 512/thr):
//  * MFMA: k in [0,128) for all 1024 gate-rows. Wave w owns row-tiles
//    4w..4w+3; 16 MFMA/wave/step (256/CU = ~1240 cy, matrix pipe). A-frags
//    live in AGPRs (64 dwords) -- read natively by MFMA, zero shuttle.
//  * VALU: k in [128,256), quarter-split (j=tid>>2, q=tid&3): 64 dot2/thread
//    = 1024 cy/SIMD (half the old floor). Weights in 64 VGPR dwords.
//  * LDS/step ~148 KB (~1500 cy): B-frags 64KB + quarter-h 64KB + gbuf 20KB;
//    all reads same-addr broadcast or disjoint-bank (upper-half h quarters
//    padded to 20 dwords), gbuf rw conflict-free.
// Partial sums meet in gbuf[row]: MFMA lanes (l&15)==0 write float4 rows,
// tail adds quad-reduced VALU partial + bias -> nonlinearity (redundant x4).
// Deferred out-store retained. Two barriers/step (gbuf, hbuf).
__launch_bounds__(1024, 1)
__global__ void lstm_main(const uint4* __restrict__ WpkA,
                          const uint4* __restrict__ WpkV,
                          const float* __restrict__ bias_sum,
                          const float* __restrict__ h_in,
                          const float* __restrict__ c_in,
                          float* __restrict__ out) {
    int b = blockIdx.x;
    int tid = threadIdx.x;
    int w = tid >> 6, l = tid & 63;
    int j = tid >> 2, q = tid & 3;
    int hb = (l >> 4) & 3;

    __shared__ unsigned hbuf[2][144];   // padded packed-half2 h (576 B each)
    __shared__ float gbuf[G4];          // MFMA partial gate sums, 4 KB

    // All weights register-resident: 16 A-frags (MFMA) + 16 VALU chunks.
    uint4 wA[16];
    #pragma unroll
    for (int fi = 0; fi < 16; ++fi) wA[fi] = WpkA[(size_t)(w * 16 + fi) * 64 + l];
    uint4 wV[16];
    #pragma unroll
    for (int n = 0; n < 16; ++n) wV[n] = WpkV[(size_t)n * 1024 + tid];

    float bias0 = bias_sum[0 * F + j];
    float bias1 = bias_sum[1 * F + j];
    float bias2 = bias_sum[2 * F + j];
    float bias3 = bias_sum[3 * F + j];
    float cj = c_in[(size_t)b * F + j];

    if (tid < 128) {
        float h0 = h_in[(size_t)b * F + 2 * tid];
        float h1 = h_in[(size_t)b * F + 2 * tid + 1];
        hbuf[0][hidx(tid)] = __builtin_bit_cast(unsigned, __floats2half2_rn(h0, h1));
    }
    __syncthreads();

    int cur = 0;
    float hprev = 0.f;  // deferred out-store value (q==1 path)
    for (int t = 1; t < S; ++t) {
        const uint4* hp4 = (const uint4*)hbuf[cur];
        // deferred store of previous step's h row: drains at bar1, hidden.
        if (q == 1 && t > 1) {
            __builtin_nontemporal_store(hprev, &out[((size_t)(t - 1) * B + b) * F + j]);
        }

        // --- MFMA half (k < 128): B-frags from contiguous pairs [0,64) ---
        uint4 Bv[4];
        #pragma unroll
        for (int kf = 0; kf < 4; ++kf) Bv[kf] = hp4[kf * 4 + hb];
        f32x4 acc0 = {0.f, 0.f, 0.f, 0.f};
        f32x4 acc1 = {0.f, 0.f, 0.f, 0.f};
        f32x4 acc2 = {0.f, 0.f, 0.f, 0.f};
        f32x4 acc3 = {0.f, 0.f, 0.f, 0.f};
        #pragma unroll
        for (int kf = 0; kf < 4; ++kf) {
            f16x8 bf = __builtin_bit_cast(f16x8, Bv[kf]);
            acc0 = __builtin_amdgcn_mfma_f32_16x16x32_f16(__builtin_bit_cast(f16x8, wA[0 + kf]), bf, acc0, 0, 0, 0);
            acc1 = __builtin_amdgcn_mfma_f32_16x16x32_f16(__builtin_bit_cast(f16x8, wA[4 + kf]), bf, acc1, 0, 0, 0);
            acc2 = __builtin_amdgcn_mfma_f32_16x16x32_f16(__builtin_bit_cast(f16x8, wA[8 + kf]), bf, acc2, 0, 0, 0);
            acc3 = __builtin_amdgcn_mfma_f32_16x16x32_f16(__builtin_bit_cast(f16x8, wA[12 + kf]), bf, acc3, 0, 0, 0);
        }

        // --- VALU half (k >= 128): quarter-h, dot2 (hides MFMA latency) ---
        uint4 hv[4];
        #pragma unroll
        for (int m = 0; m < 4; ++m) hv[m] = hp4[16 + 5 * q + m];
        float a0 = 0.f, a1 = 0.f, a2 = 0.f, a3 = 0.f;
        #pragma unroll
        for (int m = 0; m < 4; ++m) {
            uint4 h4 = hv[m];
            uint4 w0 = wV[m], w1 = wV[4 + m], w2 = wV[8 + m], w3 = wV[12 + m];
            a0 = fdot2u(w0.x, h4.x, a0); a0 = fdot2u(w0.y, h4.y, a0);
            a0 = fdot2u(w0.z, h4.z, a0); a0 = fdot2u(w0.w, h4.w, a0);
            a1 = fdot2u(w1.x, h4.x, a1); a1 = fdot2u(w1.y, h4.y, a1);
            a1 = fdot2u(w1.z, h4.z, a1); a1 = fdot2u(w1.w, h4.w, a1);
            a2 = fdot2u(w2.x, h4.x, a2); a2 = fdot2u(w2.y, h4.y, a2);
            a2 = fdot2u(w2.z, h4.z, a2); a2 = fdot2u(w2.w, h4.w, a2);
            a3 = fdot2u(w3.x, h4.x, a3); a3 = fdot2u(w3.y, h4.y, a3);
            a3 = fdot2u(w3.z, h4.z, a3); a3 = fdot2u(w3.w, h4.w, a3);
        }

        // publish MFMA partials: D row = 16*T + (l>>4)*4 + r, cols identical
        // (B broadcast) -> writer lanes (l&15)==0 store float4 per tile.
        if ((l & 15) == 0) {
            *(f32x4*)(&gbuf[(w * 4 + 0) * 16 + hb * 4]) = acc0;
            *(f32x4*)(&gbuf[(w * 4 + 1) * 16 + hb * 4]) = acc1;
            *(f32x4*)(&gbuf[(w * 4 + 2) * 16 + hb * 4]) = acc2;
            *(f32x4*)(&gbuf[(w * 4 + 3) * 16 + hb * 4]) = acc3;
        }
        __syncthreads();  // bar1: gbuf ready (also drains deferred out-store)

        // combine: quad-reduce VALU partial + MFMA partial + bias
        a0 = dpp_add<0x4E>(dpp_add<0xB1>(a0)) + bias0 + gbuf[0 * F + j];
        a1 = dpp_add<0x4E>(dpp_add<0xB1>(a1)) + bias1 + gbuf[1 * F + j];
        a2 = dpp_add<0x4E>(dpp_add<0xB1>(a2)) + bias2 + gbuf[2 * F + j];
        a3 = dpp_add<0x4E>(dpp_add<0xB1>(a3)) + bias3 + gbuf[3 * F + j];
        float c2 = sigf(a1) * cj + sigf(a0) * tanhf_fast(a2);
        float h2 = sigf(a3) * tanhf_fast(c2);
        cj = c2;
        if (q == 0) {
            ((__half*)hbuf[cur ^ 1])[hidx(j >> 1) * 2 + (j & 1)] = __float2half(h2);
        }
        hprev = h2;
        __syncthreads();  // bar2: hbuf published for next step
        cur ^= 1;
    }
    if (q == 1) {
        __builtin_nontemporal_store(hprev, &out[((size_t)(S - 1) * B + b) * F + j]);
    }
}

extern "C" void kernel_launch(void* const* d_in, const int* in_sizes, int n_in,
                              void* d_out, int out_size, void* d_ws, size_t ws_size,
                              hipStream_t stream) {
    const float* x   = (const float*)d_in[0];
    const float* lf  = (const float*)d_in[1];
    const float* Wi  = (const float*)d_in[2];
    const float* bi  = (const float*)d_in[3];
    const float* Wih = (const float*)d_in[4];
    const float* Whh = (const float*)d_in[5];
    const float* bih = (const float*)d_in[6];
    const float* bhh = (const float*)d_in[7];
    // d_in[8], d_in[9] (Wo, bo): computed-and-discarded in the reference; unused.
    float* out = (float*)d_out;

    float* ws    = (float*)d_ws;
    float* h     = ws;               // 65536 floats
    float* c     = ws + 65536;       // 65536 floats
    float* bias  = ws + 131072;      // 1024 floats
    uint4* WpkA  = (uint4*)(ws + 132096);           // 16384 uint4 = 256 KB
    uint4* WpkV  = (uint4*)(ws + 132096 + 65536);   // 16384 uint4 = 256 KB

    prep_kernel<<<128, 256, 0, stream>>>(Wih, Whh, bih, bhh, WpkA, WpkV, bias);
    init_kernel<<<B, F, 0, stream>>>(x, Wi, bi, h, c);
    step0_kernel<<<B, 1024, 0, stream>>>(lf, Wih, Whh, bias, h, c, out);
    lstm_main<<<B, 1024, 0, stream>>>(WpkA, WpkV, bias, h, c, out);
}

// Round 7
// 1210.714 us; speedup vs baseline: 3.5119x; 3.5119x over previous
//
#include <hip/hip_runtime.h>
#include <hip/hip_bf16.h>
#include <hip/hip_fp16.h>

#define B 256
#define L 128
#define F 256
#define S 512
#define G4 1024  // 4*F gate rows

typedef _Float16 h2raw __attribute__((ext_vector_type(2)));

__device__ __forceinline__ float fdot2u(unsigned a, unsigned b, float c) {
#if __has_builtin(__builtin_amdgcn_fdot2)
    return __builtin_amdgcn_fdot2(__builtin_bit_cast(h2raw, a), __builtin_bit_cast(h2raw, b), c, false);
#else
    __half2 ah = __builtin_bit_cast(__half2, a), bh = __builtin_bit_cast(__half2, b);
    float2 af = __half22float2(ah), bf = __half22float2(bh);
    return c + af.x * bf.x + af.y * bf.y;
#endif
}

// wave-uniform broadcast of lane `lane`'s dword (compile-time lane index)
__device__ __forceinline__ unsigned bcast_lane(unsigned v, int lane) {
#if __has_builtin(__builtin_amdgcn_readlane)
    return (unsigned)__builtin_amdgcn_readlane((int)v, lane);
#else
    return (unsigned)__shfl((int)v, lane, 64);
#endif
}

__device__ __forceinline__ void sched_fence() {
#if __has_builtin(__builtin_amdgcn_sched_barrier)
    __builtin_amdgcn_sched_barrier(0);
#endif
}

// fast device transcendentals: v_exp_f32 / v_rcp_f32 based
__device__ __forceinline__ float fast_rcp(float x) { return __builtin_amdgcn_rcpf(x); }
__device__ __forceinline__ float sigf(float x) {
    float e = __expf(-x);
    return fast_rcp(1.0f + e);
}
__device__ __forceinline__ float tanhf_fast(float x) {
    x = fminf(fmaxf(x, -15.0f), 15.0f);
    float e = __expf(-2.0f * x);
    return (1.0f - e) * fast_rcp(1.0f + e);
}

// partner-lane value via DPP quad_perm [1,0,3,2] (xor-1 swap)
__device__ __forceinline__ float dpp_swap1(float x) {
    int v = __builtin_amdgcn_update_dpp(0, __builtin_bit_cast(int, x), 0xB1, 0xF, 0xF, true);
    return __builtin_bit_cast(float, v);
}

// Prep v10 (GATE-split): pack combined W = W_ih + W_hh (fp16) for the
// 512-thread main kernel. Thread t: j = t>>1 (unit), q = t&1 (gate-half).
// gateA = q (i for q=0, f for q=1), gateB = 2+q (g / o); both FULL K.
// Chunk n in [0,64), Wpk[n*512+t] = 4 half2 = k-pairs of one gate row:
//   n in [ 0,16): gateA pairs 4n+{0..3}          (k = 8n+{0..7})
//   n in [16,32): gateA pairs 64+4(n-16)+{0..3}
//   n in [32,48): gateB pairs 4(n-32)+{0..3}
//   n in [48,64): gateB pairs 64+4(n-48)+{0..3}  -> streamed from LDS in main
__global__ void prep_kernel(const float* __restrict__ Wih,
                            const float* __restrict__ Whh,
                            const float* __restrict__ bih,
                            const float* __restrict__ bhh,
                            uint4* __restrict__ Wpk, float* __restrict__ bias_sum) {
    int e = blockIdx.x * blockDim.x + threadIdx.x;  // 32768 elements
    if (e < G4) bias_sum[e] = bih[e] + bhh[e];
    int n = e >> 9, t = e & 511;
    int j = t >> 1, q = t & 1;
    int sub = n >> 4;                 // 0:A-lo 1:A-hi 2:B-lo 3:B-hi
    int c = n & 15;
    int gate = (sub < 2) ? q : (2 + q);
    int p0 = ((sub & 1) ? 64 : 0) + 4 * c;   // first k-pair of this chunk
    int row = gate * F + j;
    unsigned pk[4];
    #pragma unroll
    for (int d = 0; d < 4; ++d) {
        int k = 2 * (p0 + d);
        float w0 = Wih[(size_t)row * F + k]     + Whh[(size_t)row * F + k];
        float w1 = Wih[(size_t)row * F + k + 1] + Whh[(size_t)row * F + k + 1];
        pk[d] = __builtin_bit_cast(unsigned, __floats2half2_rn(w0, w1));
    }
    Wpk[(size_t)n * 512 + t] = make_uint4(pk[0], pk[1], pk[2], pk[3]);
}

// init = elu(x[0] @ Wi.T + bi) -> h0, c0 (fp32 in workspace), float4 loads
__global__ void init_kernel(const float* __restrict__ x,
                            const float* __restrict__ Wi,
                            const float* __restrict__ bi,
                            float* __restrict__ h, float* __restrict__ c) {
    __shared__ float4 xs4[L / 4];
    int b = blockIdx.x, j = threadIdx.x;
    if (j < L / 4) xs4[j] = ((const float4*)(x + (size_t)b * L))[j];
    __syncthreads();
    float acc = bi[j];
    const float4* wp = (const float4*)(Wi + (size_t)j * L);
    #pragma unroll 8
    for (int k = 0; k < L / 4; ++k) {
        float4 w = wp[k], xv = xs4[k];
        acc += w.x * xv.x + w.y * xv.y + w.z * xv.z + w.w * xv.w;
    }
    float v = acc > 0.0f ? acc : expm1f(acc);
    h[b * F + j] = v;
    c[b * F + j] = v;
}

// Step 0: gates = last_feat @ W_ih.T + h0 @ W_hh.T + bias (fp32 exact path).
__global__ void step0_kernel(const float* __restrict__ lf,
                             const float* __restrict__ Wih,
                             const float* __restrict__ Whh,
                             const float* __restrict__ bias_sum,
                             float* __restrict__ h, float* __restrict__ c,
                             float* __restrict__ out) {
    __shared__ float vecs[2 * F];            // [inp(256) ; h0(256)]
    __shared__ float partial[3][4][F];
    int b = blockIdx.x, tid = threadIdx.x;
    int j = tid & (F - 1), q = tid >> 8;
    if (q == 0) vecs[j] = lf[(size_t)b * F + j];
    else if (q == 1) vecs[F + j] = h[(size_t)b * F + j];
    __syncthreads();
    const float* mat = (q < 2) ? Wih : Whh;
    int ks = (q & 1) * 128;
    const float4* vp = (const float4*)(&vecs[(q >> 1) * F + ks]);
    float a[4] = {0.f, 0.f, 0.f, 0.f};
    #pragma unroll
    for (int g = 0; g < 4; ++g) {
        const float4* wp = (const float4*)(&mat[(size_t)(g * F + j) * F + ks]);
        float acc = 0.f;
        #pragma unroll 8
        for (int i = 0; i < 32; ++i) {
            float4 w = wp[i], v = vp[i];
            acc += w.x * v.x + w.y * v.y + w.z * v.z + w.w * v.w;
        }
        a[g] = acc;
    }
    if (q > 0) {
        #pragma unroll
        for (int g = 0; g < 4; ++g) partial[q - 1][g][j] = a[g];
    }
    __syncthreads();
    if (q == 0) {
        #pragma unroll
        for (int g = 0; g < 4; ++g) {
            for (int p = 0; p < 3; ++p) a[g] += partial[p][g][j];
            a[g] += bias_sum[g * F + j];
        }
        float c0v = c[(size_t)b * F + j];
        float c1v = sigf(a[1]) * c0v + sigf(a[0]) * tanhf_fast(a[2]);
        float h1v = sigf(a[3]) * tanhf_fast(c1v);
        h[(size_t)b * F + j] = h1v;
        c[(size_t)b * F + j] = c1v;
        out[(size_t)b * F + j] = h1v;  // t=0 row
    }
}

// Main recurrence v10: GATE-split, wave-uniform h. 512 threads (8 waves),
// j = tid>>1 (unit), q = tid&1 (gate-half: q0={i,g}, q1={f,o}, FULL K each).
// Cycle model fitted to R0-R5 (LDS wave-b128 = 12cy): R3's binding pipe was
// LDS (256 insts = 3072 cy/step: 128 weight-stream + 128 per-lane h reads).
// Gate-split makes the h operand sequence IDENTICAL for all threads:
//  * h ingest = 2 ds_read_b32/wave (lane l holds pairs l and 64+l) + 128
//    v_readlane -> SGPR feeds fdot2 src1 directly (1-SGPR VOP3P, legal).
//    LDS h insts collapse 128 -> 16/block.
//  * No cross-thread k-reduction: partner exchange is 2 DPP quad-swaps of
//    FINISHED sums -> ONE barrier/step (ping-pong hbuf), unlike R1/R2.
//  * Weights: 192 dwords resident (gateA 32 chunks + gateB-lo 16), gateB-hi
//    streamed from LDS (128 KB, R3's measured-zero-conflict layout).
//    Liveness ~224 <= 256 (2 accs + 2 h words vs R3's 4+16): no spill.
// Deferred out-store retained (drains at the end-of-step barrier).
__launch_bounds__(512, 2)
__global__ void lstm_main(const uint4* __restrict__ Wpk,
                          const float* __restrict__ bias_sum,
                          const float* __restrict__ h_in,
                          const float* __restrict__ c_in,
                          float* __restrict__ out) {
    int b = blockIdx.x;
    int tid = threadIdx.x;
    int j = tid >> 1;
    int q = tid & 1;
    int l = tid & 63;

    __shared__ uint4 lds_wo[16][512];    // gateB hi-half weights, 128 KB
    __shared__ unsigned hbuf[2][128];    // ping-pong packed-half2 h (512 B each)

    // One-time: 48 resident chunks, 16 streamed chunks into LDS.
    uint4 wr[48];
    #pragma unroll
    for (int n = 0; n < 48; ++n) wr[n] = Wpk[(size_t)n * 512 + tid];
    #pragma unroll
    for (int m = 0; m < 16; ++m) lds_wo[m][tid] = Wpk[(size_t)(48 + m) * 512 + tid];

    // biases folded into accumulator init: q0 -> (i,g), q1 -> (f,o)
    float biasA = bias_sum[q * F + j];
    float biasB = bias_sum[(2 + q) * F + j];
    float cj = c_in[(size_t)b * F + j];

    if (tid < 128) {
        float h0 = h_in[(size_t)b * F + 2 * tid];
        float h1 = h_in[(size_t)b * F + 2 * tid + 1];
        hbuf[0][tid] = __builtin_bit_cast(unsigned, __floats2half2_rn(h0, h1));
    }
    __syncthreads();

    int cur = 0;
    float hprev = 0.f;  // deferred out-store value (q==1 path)
    for (int t = 1; t < S; ++t) {
        // h gather: lane l holds pair l (lo) and pair 64+l (hi)
        unsigned hword0 = hbuf[cur][l];
        unsigned hword1 = hbuf[cur][64 + l];
        // warm the weight stream for phase 2 under phase 1's compute
        uint4 woA = lds_wo[0][tid];
        // deferred store of previous step's h row: drains at the end-of-step
        // barrier, hidden under this step's dot2 phase.
        if (q == 1 && t > 1) {
            __builtin_nontemporal_store(hprev, &out[((size_t)(t - 1) * B + b) * F + j]);
        }

        float aA = biasA, aB = biasB;

        // Phase 1: k-pairs 0..63 (all weights register-resident)
        #pragma unroll
        for (int c = 0; c < 16; ++c) {
            uint4 wa = wr[c], wb = wr[32 + c];
            const unsigned* wap = (const unsigned*)&wa;
            const unsigned* wbp = (const unsigned*)&wb;
            #pragma unroll
            for (int d = 0; d < 4; ++d) {
                unsigned hp = bcast_lane(hword0, 4 * c + d);  // wave-uniform SGPR
                aA = fdot2u(wap[d], hp, aA);
                aB = fdot2u(wbp[d], hp, aB);
            }
        }

        // Phase 2: k-pairs 64..127 (gateA resident, gateB streamed from LDS
        // with 1-chunk lookahead to bound liveness)
        #pragma unroll
        for (int c = 0; c < 16; ++c) {
            uint4 woB;
            if (c < 15) woB = lds_wo[c + 1][tid];
            uint4 wa = wr[16 + c];
            const unsigned* wap = (const unsigned*)&wa;
            const unsigned* wop = (const unsigned*)&woA;
            #pragma unroll
            for (int d = 0; d < 4; ++d) {
                unsigned hp = bcast_lane(hword1, 4 * c + d);
                aA = fdot2u(wap[d], hp, aA);
                aB = fdot2u(wop[d], hp, aB);
            }
            woA = woB;
            sched_fence();  // keep chunk c+1's load from hoisting further up
        }

        // partner exchange (q0 holds i,g; q1 holds f,o) -> all 4 sums
        float bA = dpp_swap1(aA);   // partner's gateA sum
        float bB = dpp_swap1(aB);   // partner's gateB sum
        float i_s = q ? bA : aA;
        float f_s = q ? aA : bA;
        float g_s = q ? bB : aB;
        float o_s = q ? aB : bB;
        float c2 = sigf(f_s) * cj + sigf(i_s) * tanhf_fast(g_s);
        float h2 = sigf(o_s) * tanhf_fast(c2);
        cj = c2;
        if (q == 0) ((__half*)hbuf[cur ^ 1])[j] = __float2half(h2);
        hprev = h2;
        __syncthreads();   // single barrier: publishes hbuf, drains out-store
        cur ^= 1;
    }
    if (q == 1) {
        __builtin_nontemporal_store(hprev, &out[((size_t)(S - 1) * B + b) * F + j]);
    }
}

extern "C" void kernel_launch(void* const* d_in, const int* in_sizes, int n_in,
                              void* d_out, int out_size, void* d_ws, size_t ws_size,
                              hipStream_t stream) {
    const float* x   = (const float*)d_in[0];
    const float* lf  = (const float*)d_in[1];
    const float* Wi  = (const float*)d_in[2];
    const float* bi  = (const float*)d_in[3];
    const float* Wih = (const float*)d_in[4];
    const float* Whh = (const float*)d_in[5];
    const float* bih = (const float*)d_in[6];
    const float* bhh = (const float*)d_in[7];
    // d_in[8], d_in[9] (Wo, bo): computed-and-discarded in the reference; unused.
    float* out = (float*)d_out;

    float* ws    = (float*)d_ws;
    float* h     = ws;               // 65536 floats
    float* c     = ws + 65536;       // 65536 floats
    float* bias  = ws + 131072;      // 1024 floats
    uint4* Wpk   = (uint4*)(ws + 132096);  // 64 chunks x 512 x 16B = 512 KB

    prep_kernel<<<128, 256, 0, stream>>>(Wih, Whh, bih, bhh, Wpk, bias);
    init_kernel<<<B, F, 0, stream>>>(x, Wi, bi, h, c);
    step0_kernel<<<B, 1024, 0, stream>>>(lf, Wih, Whh, bias, h, c, out);
    lstm_main<<<B, 512, 0, stream>>>(Wpk, bias, h, c, out);
}

// Round 8
// 995.475 us; speedup vs baseline: 4.2712x; 1.2162x over previous
//
#include <hip/hip_runtime.h>
#include <hip/hip_bf16.h>
#include <hip/hip_fp16.h>

#define B 256
#define L 128
#define F 256
#define S 512
#define G4 1024  // 4*F gate rows

typedef _Float16 h2raw __attribute__((ext_vector_type(2)));

__device__ __forceinline__ float fdot2u(unsigned a, unsigned b, float c) {
#if __has_builtin(__builtin_amdgcn_fdot2)
    return __builtin_amdgcn_fdot2(__builtin_bit_cast(h2raw, a), __builtin_bit_cast(h2raw, b), c, false);
#else
    __half2 ah = __builtin_bit_cast(__half2, a), bh = __builtin_bit_cast(__half2, b);
    float2 af = __half22float2(ah), bf = __half22float2(bh);
    return c + af.x * bf.x + af.y * bf.y;
#endif
}

// fast device transcendentals: v_exp_f32 / v_rcp_f32 based
__device__ __forceinline__ float fast_rcp(float x) { return __builtin_amdgcn_rcpf(x); }
__device__ __forceinline__ float sigf(float x) {
    float e = __expf(-x);
    return fast_rcp(1.0f + e);
}
__device__ __forceinline__ float tanhf_fast(float x) {
    x = fminf(fmaxf(x, -15.0f), 15.0f);
    float e = __expf(-2.0f * x);
    return (1.0f - e) * fast_rcp(1.0f + e);
}

template <int CTRL>
__device__ __forceinline__ float dpp_add(float x) {
    int v = __builtin_amdgcn_update_dpp(0, __builtin_bit_cast(int, x), CTRL, 0xF, 0xF, true);
    return x + __builtin_bit_cast(float, v);
}

// Prep (R3 layout, unchanged): pack combined W = W_ih + W_hh.
// Thread mapping: j = tid>>1 (hidden unit), q = tid&1 (k-half).
// Chunk n in [0,64): n<48 -> register gates g=n>>4 (i,f,g), m=n&15;
//                    n>=48 -> gate g=3 (o), m=n-48 (m<8: LDS, m>=8: L2-stream).
// Wpk[n*512+tid] = 4 half2 = k-pairs kp = q*64 + m*4 + {0..3} of row g*256+j.
__global__ void prep_kernel(const float* __restrict__ Wih,
                            const float* __restrict__ Whh,
                            const float* __restrict__ bih,
                            const float* __restrict__ bhh,
                            uint4* __restrict__ Wpk, float* __restrict__ bias_sum) {
    int e = blockIdx.x * blockDim.x + threadIdx.x;  // 32768 elements
    if (e < G4) bias_sum[e] = bih[e] + bhh[e];
    int n = e >> 9, tid = e & 511;
    int j = tid >> 1, q = tid & 1;
    int g = (n < 48) ? (n >> 4) : 3;
    int m = (n < 48) ? (n & 15) : (n - 48);
    int r = g * F + j;
    int kp0 = q * 64 + m * 4;
    unsigned pk[4];
    #pragma unroll
    for (int i = 0; i < 4; ++i) {
        int k = 2 * (kp0 + i);
        float w0 = Wih[(size_t)r * F + k]     + Whh[(size_t)r * F + k];
        float w1 = Wih[(size_t)r * F + k + 1] + Whh[(size_t)r * F + k + 1];
        pk[i] = __builtin_bit_cast(unsigned, __floats2half2_rn(w0, w1));
    }
    Wpk[(size_t)n * 512 + tid] = make_uint4(pk[0], pk[1], pk[2], pk[3]);
}

// init = elu(x[0] @ Wi.T + bi) -> h0, c0 (fp32 in workspace), float4 loads
__global__ void init_kernel(const float* __restrict__ x,
                            const float* __restrict__ Wi,
                            const float* __restrict__ bi,
                            float* __restrict__ h, float* __restrict__ c) {
    __shared__ float4 xs4[L / 4];
    int b = blockIdx.x, j = threadIdx.x;
    if (j < L / 4) xs4[j] = ((const float4*)(x + (size_t)b * L))[j];
    __syncthreads();
    float acc = bi[j];
    const float4* wp = (const float4*)(Wi + (size_t)j * L);
    #pragma unroll 8
    for (int k = 0; k < L / 4; ++k) {
        float4 w = wp[k], xv = xs4[k];
        acc += w.x * xv.x + w.y * xv.y + w.z * xv.z + w.w * xv.w;
    }
    float v = acc > 0.0f ? acc : expm1f(acc);
    h[b * F + j] = v;
    c[b * F + j] = v;
}

// Step 0: gates = last_feat @ W_ih.T + h0 @ W_hh.T + bias (fp32 exact path).
__global__ void step0_kernel(const float* __restrict__ lf,
                             const float* __restrict__ Wih,
                             const float* __restrict__ Whh,
                             const float* __restrict__ bias_sum,
                             float* __restrict__ h, float* __restrict__ c,
                             float* __restrict__ out) {
    __shared__ float vecs[2 * F];            // [inp(256) ; h0(256)]
    __shared__ float partial[3][4][F];
    int b = blockIdx.x, tid = threadIdx.x;
    int j = tid & (F - 1), q = tid >> 8;
    if (q == 0) vecs[j] = lf[(size_t)b * F + j];
    else if (q == 1) vecs[F + j] = h[(size_t)b * F + j];
    __syncthreads();
    const float* mat = (q < 2) ? Wih : Whh;
    int ks = (q & 1) * 128;
    const float4* vp = (const float4*)(&vecs[(q >> 1) * F + ks]);
    float a[4] = {0.f, 0.f, 0.f, 0.f};
    #pragma unroll
    for (int g = 0; g < 4; ++g) {
        const float4* wp = (const float4*)(&mat[(size_t)(g * F + j) * F + ks]);
        float acc = 0.f;
        #pragma unroll 8
        for (int i = 0; i < 32; ++i) {
            float4 w = wp[i], v = vp[i];
            acc += w.x * v.x + w.y * v.y + w.z * v.z + w.w * v.w;
        }
        a[g] = acc;
    }
    if (q > 0) {
        #pragma unroll
        for (int g = 0; g < 4; ++g) partial[q - 1][g][j] = a[g];
    }
    __syncthreads();
    if (q == 0) {
        #pragma unroll
        for (int g = 0; g < 4; ++g) {
            for (int p = 0; p < 3; ++p) a[g] += partial[p][g][j];
            a[g] += bias_sum[g * F + j];
        }
        float c0v = c[(size_t)b * F + j];
        float c1v = sigf(a[1]) * c0v + sigf(a[0]) * tanhf_fast(a[2]);
        float h1v = sigf(a[3]) * tanhf_fast(c1v);
        h[(size_t)b * F + j] = h1v;
        c[(size_t)b * F + j] = c1v;
        out[(size_t)b * F + j] = h1v;  // t=0 row
    }
}

// Main recurrence v11: R3 structure (best measured, 790us) with the o-gate
// weight stream REBALANCED off the LDS pipe. R3's pipe budget: LDS 3072
// cy/CU/step (32 wave-b128/thread: 16 hv + 16 wo) vs VALU 2810 cy/SIMD --
// two-pipe bind at 83%/76% of the 3710 wall. Changes:
//  * o-gate chunks 8..15 stream from GLOBAL (L2-hot: same 64 KB for every
//    block, fits each XCD L2) on the idle vmem pipe. 64 KB/step/CU ~= 1170cy
//    at the 56 B/cy/CU L2 share -> hidden. LDS drops 3072 -> 2304 cy.
//  * Global loads issued in 2 groups of 4, placed 4 / 2 chunks (~700/~350cy)
//    ahead of first use -> covers L2 latency (~200-350cy); compiler vmcnt.
//  * Manual hv/wo double-buffer + fences dropped (regs freed for the load
//    groups); plain unrolled chunks, literal-indexed (no dyn VGPR indexing).
// hbuf bank-pad + deferred out-store + DPP reduce + 1 barrier: unchanged R3.
__launch_bounds__(512, 2)
__global__ void lstm_main(const uint4* __restrict__ Wpk,
                          const float* __restrict__ bias_sum,
                          const float* __restrict__ h_in,
                          const float* __restrict__ c_in,
                          float* __restrict__ out) {
    int b = blockIdx.x;
    int tid = threadIdx.x;
    int j = tid >> 1;
    int q = tid & 1;

    __shared__ uint4 lds_wo[8][512];    // gate-o chunks 0..7, 64 KB
    __shared__ uint4 hbuf4[2][34];      // 2 bufs x (2 halves x 17 uint4, 16B pad)

    // One-time: gates i,f,g into registers; gate-o chunks 0..7 into LDS.
    uint4 wr[48];
    #pragma unroll
    for (int n = 0; n < 48; ++n) wr[n] = Wpk[(size_t)n * 512 + tid];
    #pragma unroll
    for (int m = 0; m < 8; ++m) lds_wo[m][tid] = Wpk[(size_t)(48 + m) * 512 + tid];
    // gate-o chunks 8..15 (prep chunks 56..63): streamed from L2 each step
    const uint4* gw = Wpk + (size_t)56 * 512 + tid;

    float bias0 = bias_sum[0 * F + j];
    float bias1 = bias_sum[1 * F + j];
    float bias2 = bias_sum[2 * F + j];
    float bias3 = bias_sum[3 * F + j];
    float cj = c_in[(size_t)b * F + j];

    if (tid < F) {
        __half* hp = (__half*)&hbuf4[0][(tid >> 7) * 17];
        hp[tid & 127] = __float2half(h_in[(size_t)b * F + tid]);
    }
    __syncthreads();

    int cur = 0;
    float hprev = 0.f;  // deferred out-store value (q==1 path)
    for (int t = 1; t < S; ++t) {
        const uint4* hb = &hbuf4[cur][q * 17];
        // deferred store of previous step's h row: drains at the end-of-step
        // barrier ~a full step after issue -> hidden.
        if (q == 1 && t > 1) {
            __builtin_nontemporal_store(hprev, &out[((size_t)(t - 1) * B + b) * F + j]);
        }
        float a0 = 0.f, a1 = 0.f, a2 = 0.f, a3 = 0.f;

#define CHUNK(i, w3v)                                                      \
        {                                                                  \
            uint4 hv = hb[i];                                              \
            uint4 w0 = wr[i];                                              \
            uint4 w1 = wr[16 + (i)];                                       \
            uint4 w2 = wr[32 + (i)];                                       \
            uint4 w3 = (w3v);                                              \
            a0 = fdot2u(w0.x, hv.x, a0); a0 = fdot2u(w0.y, hv.y, a0);      \
            a0 = fdot2u(w0.z, hv.z, a0); a0 = fdot2u(w0.w, hv.w, a0);      \
            a1 = fdot2u(w1.x, hv.x, a1); a1 = fdot2u(w1.y, hv.y, a1);      \
            a1 = fdot2u(w1.z, hv.z, a1); a1 = fdot2u(w1.w, hv.w, a1);      \
            a2 = fdot2u(w2.x, hv.x, a2); a2 = fdot2u(w2.y, hv.y, a2);      \
            a2 = fdot2u(w2.z, hv.z, a2); a2 = fdot2u(w2.w, hv.w, a2);      \
            a3 = fdot2u(w3.x, hv.x, a3); a3 = fdot2u(w3.y, hv.y, a3);      \
            a3 = fdot2u(w3.z, hv.z, a3); a3 = fdot2u(w3.w, hv.w, a3);      \
        }

        CHUNK(0, lds_wo[0][tid])
        CHUNK(1, lds_wo[1][tid])
        CHUNK(2, lds_wo[2][tid])
        CHUNK(3, lds_wo[3][tid])
        // issue global group A (o-gate k-chunks 8..11), ~4 chunks ahead
        uint4 gA0 = gw[0 * 512], gA1 = gw[1 * 512], gA2 = gw[2 * 512], gA3 = gw[3 * 512];
        CHUNK(4, lds_wo[4][tid])
        CHUNK(5, lds_wo[5][tid])
        CHUNK(6, lds_wo[6][tid])
        CHUNK(7, lds_wo[7][tid])
        // issue global group B (o-gate k-chunks 12..15), ~2 chunks ahead
        uint4 gB0 = gw[4 * 512], gB1 = gw[5 * 512], gB2 = gw[6 * 512], gB3 = gw[7 * 512];
        CHUNK(8, gA0)
        CHUNK(9, gA1)
        CHUNK(10, gA2)
        CHUNK(11, gA3)
        CHUNK(12, gB0)
        CHUNK(13, gB1)
        CHUNK(14, gB2)
        CHUNK(15, gB3)
#undef CHUNK

        // sum the 2 k-halves (lane pairs); both lanes get full sums
        a0 = dpp_add<0xB1>(a0) + bias0;
        a1 = dpp_add<0xB1>(a1) + bias1;
        a2 = dpp_add<0xB1>(a2) + bias2;
        a3 = dpp_add<0xB1>(a3) + bias3;
        float c2 = sigf(a1) * cj + sigf(a0) * tanhf_fast(a2);
        float h2 = sigf(a3) * tanhf_fast(c2);
        cj = c2;
        if (q == 0) {
            __half* hp = (__half*)&hbuf4[cur ^ 1][(j >> 7) * 17];
            hp[j & 127] = __float2half(h2);
        }
        hprev = h2;
        __syncthreads();
        cur ^= 1;
    }
    if (q == 1) {
        __builtin_nontemporal_store(hprev, &out[((size_t)(S - 1) * B + b) * F + j]);
    }
}

extern "C" void kernel_launch(void* const* d_in, const int* in_sizes, int n_in,
                              void* d_out, int out_size, void* d_ws, size_t ws_size,
                              hipStream_t stream) {
    const float* x   = (const float*)d_in[0];
    const float* lf  = (const float*)d_in[1];
    const float* Wi  = (const float*)d_in[2];
    const float* bi  = (const float*)d_in[3];
    const float* Wih = (const float*)d_in[4];
    const float* Whh = (const float*)d_in[5];
    const float* bih = (const float*)d_in[6];
    const float* bhh = (const float*)d_in[7];
    // d_in[8], d_in[9] (Wo, bo): computed-and-discarded in the reference; unused.
    float* out = (float*)d_out;

    float* ws    = (float*)d_ws;
    float* h     = ws;               // 65536 floats
    float* c     = ws + 65536;       // 65536 floats
    float* bias  = ws + 131072;      // 1024 floats
    uint4* Wpk   = (uint4*)(ws + 132096);  // 64 chunks x 512 x 16B = 512 KB

    prep_kernel<<<128, 256, 0, stream>>>(Wih, Whh, bih, bhh, Wpk, bias);
    init_kernel<<<B, F, 0, stream>>>(x, Wi, bi, h, c);
    step0_kernel<<<B, 1024, 0, stream>>>(lf, Wih, Whh, bias, h, c, out);
    lstm_main<<<B, 512, 0, stream>>>(Wpk, bias, h, c, out);
}

// Round 10
// 923.237 us; speedup vs baseline: 4.6054x; 1.0782x over previous
//
#include <hip/hip_runtime.h>
#include <hip/hip_bf16.h>
#include <hip/hip_fp16.h>

#define B 256
#define L 128
#define F 256
#define S 512
#define G4 1024  // 4*F gate rows

typedef _Float16 h2raw __attribute__((ext_vector_type(2)));

__device__ __forceinline__ float fdot2u(unsigned a, unsigned b, float c) {
#if __has_builtin(__builtin_amdgcn_fdot2)
    return __builtin_amdgcn_fdot2(__builtin_bit_cast(h2raw, a), __builtin_bit_cast(h2raw, b), c, false);
#else
    __half2 ah = __builtin_bit_cast(__half2, a), bh = __builtin_bit_cast(__half2, b);
    float2 af = __half22float2(ah), bf = __half22float2(bh);
    return c + af.x * bf.x + af.y * bf.y;
#endif
}

__device__ __forceinline__ void sched_fence() {
#if __has_builtin(__builtin_amdgcn_sched_barrier)
    __builtin_amdgcn_sched_barrier(0);
#endif
}

// fast device transcendentals: v_exp_f32 / v_rcp_f32 based
__device__ __forceinline__ float fast_rcp(float x) { return __builtin_amdgcn_rcpf(x); }
__device__ __forceinline__ float sigf(float x) {
    float e = __expf(-x);
    return fast_rcp(1.0f + e);
}
__device__ __forceinline__ float tanhf_fast(float x) {
    x = fminf(fmaxf(x, -15.0f), 15.0f);
    float e = __expf(-2.0f * x);
    return (1.0f - e) * fast_rcp(1.0f + e);
}

template <int CTRL>
__device__ __forceinline__ float dpp_add(float x) {
    int v = __builtin_amdgcn_update_dpp(0, __builtin_bit_cast(int, x), CTRL, 0xF, 0xF, true);
    return x + __builtin_bit_cast(float, v);
}

// Prep v12: pack combined W = W_ih + W_hh (fp16) for the R_T=8 main kernel.
// Thread t: ug = t>>2 (unit pair: units 2ug, 2ug+1), q = t&3 (k-QUARTER).
// Chunk n in [0,64), Wpk[n*512+t] = 4 half2 = k-pairs kp = q*32+m*4+{0..3}:
//   n <  48: resident. n = r*8+m, r = g*2+u (g in {i,f,g}, u in {0,1}):
//            row = g*256 + 2*ug + u.
//   n >= 48: streamed o-gate. n-48 = u*8+m: row = 768 + 2*ug + u.
__global__ void prep_kernel(const float* __restrict__ Wih,
                            const float* __restrict__ Whh,
                            const float* __restrict__ bih,
                            const float* __restrict__ bhh,
                            uint4* __restrict__ Wpk, float* __restrict__ bias_sum) {
    int e = blockIdx.x * blockDim.x + threadIdx.x;  // 32768 elements
    if (e < G4) bias_sum[e] = bih[e] + bhh[e];
    int n = e >> 9, t = e & 511;
    int ug = t >> 2, q = t & 3;
    int g, u, m;
    if (n < 48) {
        int r = n >> 3;
        m = n & 7;
        g = r >> 1;
        u = r & 1;
    } else {
        int m2 = n - 48;
        u = m2 >> 3;
        m = m2 & 7;
        g = 3;
    }
    int row = g * F + 2 * ug + u;
    int kp0 = q * 32 + m * 4;
    unsigned pk[4];
    #pragma unroll
    for (int i = 0; i < 4; ++i) {
        int k = 2 * (kp0 + i);
        float w0 = Wih[(size_t)row * F + k]     + Whh[(size_t)row * F + k];
        float w1 = Wih[(size_t)row * F + k + 1] + Whh[(size_t)row * F + k + 1];
        pk[i] = __builtin_bit_cast(unsigned, __floats2half2_rn(w0, w1));
    }
    Wpk[(size_t)n * 512 + t] = make_uint4(pk[0], pk[1], pk[2], pk[3]);
}

// init = elu(x[0] @ Wi.T + bi) -> h0, c0 (fp32 in workspace), float4 loads
__global__ void init_kernel(const float* __restrict__ x,
                            const float* __restrict__ Wi,
                            const float* __restrict__ bi,
                            float* __restrict__ h, float* __restrict__ c) {
    __shared__ float4 xs4[L / 4];
    int b = blockIdx.x, j = threadIdx.x;
    if (j < L / 4) xs4[j] = ((const float4*)(x + (size_t)b * L))[j];
    __syncthreads();
    float acc = bi[j];
    const float4* wp = (const float4*)(Wi + (size_t)j * L);
    #pragma unroll 8
    for (int k = 0; k < L / 4; ++k) {
        float4 w = wp[k], xv = xs4[k];
        acc += w.x * xv.x + w.y * xv.y + w.z * xv.z + w.w * xv.w;
    }
    float v = acc > 0.0f ? acc : expm1f(acc);
    h[b * F + j] = v;
    c[b * F + j] = v;
}

// Step 0: gates = last_feat @ W_ih.T + h0 @ W_hh.T + bias (fp32 exact path).
__global__ void step0_kernel(const float* __restrict__ lf,
                             const float* __restrict__ Wih,
                             const float* __restrict__ Whh,
                             const float* __restrict__ bias_sum,
                             float* __restrict__ h, float* __restrict__ c,
                             float* __restrict__ out) {
    __shared__ float vecs[2 * F];            // [inp(256) ; h0(256)]
    __shared__ float partial[3][4][F];
    int b = blockIdx.x, tid = threadIdx.x;
    int j = tid & (F - 1), q = tid >> 8;
    if (q == 0) vecs[j] = lf[(size_t)b * F + j];
    else if (q == 1) vecs[F + j] = h[(size_t)b * F + j];
    __syncthreads();
    const float* mat = (q < 2) ? Wih : Whh;
    int ks = (q & 1) * 128;
    const float4* vp = (const float4*)(&vecs[(q >> 1) * F + ks]);
    float a[4] = {0.f, 0.f, 0.f, 0.f};
    #pragma unroll
    for (int g = 0; g < 4; ++g) {
        const float4* wp = (const float4*)(&mat[(size_t)(g * F + j) * F + ks]);
        float acc = 0.f;
        #pragma unroll 8
        for (int i = 0; i < 32; ++i) {
            float4 w = wp[i], v = vp[i];
            acc += w.x * v.x + w.y * v.y + w.z * v.z + w.w * v.w;
        }
        a[g] = acc;
    }
    if (q > 0) {
        #pragma unroll
        for (int g = 0; g < 4; ++g) partial[q - 1][g][j] = a[g];
    }
    __syncthreads();
    if (q == 0) {
        #pragma unroll
        for (int g = 0; g < 4; ++g) {
            for (int p = 0; p < 3; ++p) a[g] += partial[p][g][j];
            a[g] += bias_sum[g * F + j];
        }
        float c0v = c[(size_t)b * F + j];
        float c1v = sigf(a[1]) * c0v + sigf(a[0]) * tanhf_fast(a[2]);
        float h1v = sigf(a[3]) * tanhf_fast(c1v);
        h[(size_t)b * F + j] = h1v;
        c[(size_t)b * F + j] = c1v;
        out[(size_t)b * F + j] = h1v;  // t=0 row
    }
}

// Main recurrence v12: R_T=8 remap of the proven R3 structure.
// Thread t: ug = t>>2 (2 units), q = t&3 (k-quarter). 8 gate-rows/thread
// (2 units x 4 gates) over 32 k-pairs. Rationale (model fitted to R0-R8):
// hv LDS traffic scales as 1/(rows per thread) -- R3's 16 hv b128 reads
// per thread drop to 8 here, cutting LDS 3072 -> 2304 cy/CU/step (below
// VALU ~3030), at identical fdot2 count and identical 192/64 weight split.
//  * reduction is quad-local (threads 4ug..4ug+3 = one quad): R5's proven
//    xor1 (0xB1) + xor2 (0x4E) DPP over 8 accumulators.
//  * h quarters padded to 36 dwords (R5's layout, measured 0 conflicts):
//    4 broadcast groups hit disjoint bank quartets.
//  * rolling 1-ahead hv/wo prefetch + sched fences, with wo wraparound at
//    m=7 loading NEXT STEP's m=0 chunks -> those ds_reads complete at the
//    barrier's lgkmcnt(0) drain and fill part of the serial tail (R3 idiom).
//  * deferred out-store, single barrier, ping-pong hbuf: unchanged R3.
// Lane roles per quad: usel=(t>>1)&1 picks the lane's unit (2ug+usel);
// (t&1)==0 lanes write hbuf halves, (t&1)==1 lanes own the out-store.
__launch_bounds__(512, 2)
__global__ void lstm_main(const uint4* __restrict__ Wpk,
                          const float* __restrict__ bias_sum,
                          const float* __restrict__ h_in,
                          const float* __restrict__ c_in,
                          float* __restrict__ out) {
    int b = blockIdx.x;
    int tid = threadIdx.x;
    int ug = tid >> 2;
    int q = tid & 3;
    int usel = (tid >> 1) & 1;
    int ju = 2 * ug + usel;           // this lane's unit

    __shared__ uint4 lds_wo[16][512];   // streamed o-gate chunks, 128 KB
    __shared__ unsigned hbuf[2][144];   // 2 bufs x 4 quarters x 36 dwords (pad)

    // One-time: 48 resident chunks (i,f,g x 2 units), 16 streamed into LDS.
    uint4 wr[48];
    #pragma unroll
    for (int n = 0; n < 48; ++n) wr[n] = Wpk[(size_t)n * 512 + tid];
    #pragma unroll
    for (int m2 = 0; m2 < 16; ++m2) lds_wo[m2][tid] = Wpk[(size_t)(48 + m2) * 512 + tid];

    // per-lane biases for its own unit's 4 gates (applied post-reduce)
    float biasI = bias_sum[0 * F + ju];
    float biasF = bias_sum[1 * F + ju];
    float biasG = bias_sum[2 * F + ju];
    float biasO = bias_sum[3 * F + ju];
    float cj = c_in[(size_t)b * F + ju];

    // initial h fill: unit j -> pair p=j>>1 at dword (p>>5)*36+(p&31), half j&1
    if (tid < F) {
        int p = tid >> 1;
        ((__half*)&hbuf[0][(p >> 5) * 36 + (p & 31)])[tid & 1] =
            __float2half(h_in[(size_t)b * F + tid]);
    }
    __syncthreads();

    int cur = 0;
    float hprev = 0.f;  // deferred out-store value ((tid&1)==1 path)
    for (int t = 1; t < S; ++t) {
        const uint4* hq4 = (const uint4*)(hbuf[cur] + q * 36);
        // deferred store of previous step's h row: drains at the end-of-step
        // barrier ~a full step after issue -> hidden.
        if ((tid & 1) == 1 && t > 1) {
            __builtin_nontemporal_store(hprev, &out[((size_t)(t - 1) * B + b) * F + ju]);
        }
        float a0A = 0.f, a0B = 0.f, a1A = 0.f, a1B = 0.f;
        float a2A = 0.f, a2B = 0.f, a3A = 0.f, a3B = 0.f;

        uint4 hvA = hq4[0];
        uint4 woA0 = lds_wo[0][tid], woA1 = lds_wo[8][tid];
        #pragma unroll
        for (int m = 0; m < 8; ++m) {
            uint4 hvB, woB0, woB1;
            if (m < 7) {
                hvB = hq4[m + 1];
                woB0 = lds_wo[m + 1][tid];
                woB1 = lds_wo[9 + m][tid];
            } else {            // cross-barrier prefetch: next step's m=0
                hvB = hvA;      // unused
                woB0 = lds_wo[0][tid];
                woB1 = lds_wo[8][tid];
            }
            {
                uint4 hv = hvA;
                uint4 wiA = wr[m],      wiB = wr[8 + m];
                uint4 wfA = wr[16 + m], wfB = wr[24 + m];
                uint4 wgA = wr[32 + m], wgB = wr[40 + m];
                a0A = fdot2u(wiA.x, hv.x, a0A); a0A = fdot2u(wiA.y, hv.y, a0A);
                a0A = fdot2u(wiA.z, hv.z, a0A); a0A = fdot2u(wiA.w, hv.w, a0A);
                a0B = fdot2u(wiB.x, hv.x, a0B); a0B = fdot2u(wiB.y, hv.y, a0B);
                a0B = fdot2u(wiB.z, hv.z, a0B); a0B = fdot2u(wiB.w, hv.w, a0B);
                a1A = fdot2u(wfA.x, hv.x, a1A); a1A = fdot2u(wfA.y, hv.y, a1A);
                a1A = fdot2u(wfA.z, hv.z, a1A); a1A = fdot2u(wfA.w, hv.w, a1A);
                a1B = fdot2u(wfB.x, hv.x, a1B); a1B = fdot2u(wfB.y, hv.y, a1B);
                a1B = fdot2u(wfB.z, hv.z, a1B); a1B = fdot2u(wfB.w, hv.w, a1B);
                a2A = fdot2u(wgA.x, hv.x, a2A); a2A = fdot2u(wgA.y, hv.y, a2A);
                a2A = fdot2u(wgA.z, hv.z, a2A); a2A = fdot2u(wgA.w, hv.w, a2A);
                a2B = fdot2u(wgB.x, hv.x, a2B); a2B = fdot2u(wgB.y, hv.y, a2B);
                a2B = fdot2u(wgB.z, hv.z, a2B); a2B = fdot2u(wgB.w, hv.w, a2B);
                a3A = fdot2u(woA0.x, hv.x, a3A); a3A = fdot2u(woA0.y, hv.y, a3A);
                a3A = fdot2u(woA0.z, hv.z, a3A); a3A = fdot2u(woA0.w, hv.w, a3A);
                a3B = fdot2u(woA1.x, hv.x, a3B); a3B = fdot2u(woA1.y, hv.y, a3B);
                a3B = fdot2u(woA1.z, hv.z, a3B); a3B = fdot2u(woA1.w, hv.w, a3B);
            }
            hvA = hvB; woA0 = woB0; woA1 = woB1;
            sched_fence();  // keep chunk m+1's loads from hoisting further up
        }

        // quad reduction over the 4 k-quarters; all 4 lanes get full sums
        a0A = dpp_add<0x4E>(dpp_add<0xB1>(a0A));
        a0B = dpp_add<0x4E>(dpp_add<0xB1>(a0B));
        a1A = dpp_add<0x4E>(dpp_add<0xB1>(a1A));
        a1B = dpp_add<0x4E>(dpp_add<0xB1>(a1B));
        a2A = dpp_add<0x4E>(dpp_add<0xB1>(a2A));
        a2B = dpp_add<0x4E>(dpp_add<0xB1>(a2B));
        a3A = dpp_add<0x4E>(dpp_add<0xB1>(a3A));
        a3B = dpp_add<0x4E>(dpp_add<0xB1>(a3B));

        // select this lane's unit and finish
        float aI = (usel ? a0B : a0A) + biasI;
        float aF = (usel ? a1B : a1A) + biasF;
        float aG = (usel ? a2B : a2A) + biasG;
        float aO = (usel ? a3B : a3A) + biasO;
        float c2 = sigf(aF) * cj + sigf(aI) * tanhf_fast(aG);
        float h2 = sigf(aO) * tanhf_fast(c2);
        cj = c2;
        if ((tid & 1) == 0) {
            ((__half*)&hbuf[cur ^ 1][(ug >> 5) * 36 + (ug & 31)])[usel] = __float2half(h2);
        }
        hprev = h2;
        __syncthreads();
        cur ^= 1;
    }
    if ((tid & 1) == 1) {
        __builtin_nontemporal_store(hprev, &out[((size_t)(S - 1) * B + b) * F + ju]);
    }
}

extern "C" void kernel_launch(void* const* d_in, const int* in_sizes, int n_in,
                              void* d_out, int out_size, void* d_ws, size_t ws_size,
                              hipStream_t stream) {
    const float* x   = (const float*)d_in[0];
    const float* lf  = (const float*)d_in[1];
    const float* Wi  = (const float*)d_in[2];
    const float* bi  = (const float*)d_in[3];
    const float* Wih = (const float*)d_in[4];
    const float* Whh = (const float*)d_in[5];
    const float* bih = (const float*)d_in[6];
    const float* bhh = (const float*)d_in[7];
    // d_in[8], d_in[9] (Wo, bo): computed-and-discarded in the reference; unused.
    float* out = (float*)d_out;

    float* ws    = (float*)d_ws;
    float* h     = ws;               // 65536 floats
    float* c     = ws + 65536;       // 65536 floats
    float* bias  = ws + 131072;      // 1024 floats
    uint4* Wpk   = (uint4*)(ws + 132096);  // 64 chunks x 512 x 16B = 512 KB

    prep_kernel<<<128, 256, 0, stream>>>(Wih, Whh, bih, bhh, Wpk, bias);
    init_kernel<<<B, F, 0, stream>>>(x, Wi, bi, h, c);
    step0_kernel<<<B, 1024, 0, stream>>>(lf, Wih, Whh, bias, h, c, out);
    lstm_main<<<B, 512, 0, stream>>>(Wpk, bias, h, c, out);
}

// Round 11
// 873.482 us; speedup vs baseline: 4.8677x; 1.0570x over previous
//
#include <hip/hip_runtime.h>
#include <hip/hip_bf16.h>
#include <hip/hip_fp16.h>

#define B 256
#define L 128
#define F 256
#define S 512
#define G4 1024  // 4*F gate rows

typedef _Float16 h2raw __attribute__((ext_vector_type(2)));

__device__ __forceinline__ float fdot2u(unsigned a, unsigned b, float c) {
#if __has_builtin(__builtin_amdgcn_fdot2)
    return __builtin_amdgcn_fdot2(__builtin_bit_cast(h2raw, a), __builtin_bit_cast(h2raw, b), c, false);
#else
    __half2 ah = __builtin_bit_cast(__half2, a), bh = __builtin_bit_cast(__half2, b);
    float2 af = __half22float2(ah), bf = __half22float2(bh);
    return c + af.x * bf.x + af.y * bf.y;
#endif
}

__device__ __forceinline__ void sched_fence() {
#if __has_builtin(__builtin_amdgcn_sched_barrier)
    __builtin_amdgcn_sched_barrier(0);
#endif
}

// fast device transcendentals: v_exp_f32 / v_rcp_f32 based
__device__ __forceinline__ float fast_rcp(float x) { return __builtin_amdgcn_rcpf(x); }
__device__ __forceinline__ float sigf(float x) {
    float e = __expf(-x);
    return fast_rcp(1.0f + e);
}
__device__ __forceinline__ float tanhf_fast(float x) {
    x = fminf(fmaxf(x, -15.0f), 15.0f);
    float e = __expf(-2.0f * x);
    return (1.0f - e) * fast_rcp(1.0f + e);
}

template <int CTRL>
__device__ __forceinline__ float dpp_add(float x) {
    int v = __builtin_amdgcn_update_dpp(0, __builtin_bit_cast(int, x), CTRL, 0xF, 0xF, true);
    return x + __builtin_bit_cast(float, v);
}

// Prep (R3 layout, unchanged): pack combined W = W_ih + W_hh.
// Thread mapping: j = tid>>1 (hidden unit), q = tid&1 (k-half).
// Chunk n in [0,64): n<48 -> register gates g=n>>4 (i,f,g), m=n&15;
//                    n>=48 -> LDS gate g=3 (o), m=n-48.
// Wpk[n*512+tid] = 4 half2 = k-pairs kp = q*64 + m*4 + {0..3} of row g*256+j.
__global__ void prep_kernel(const float* __restrict__ Wih,
                            const float* __restrict__ Whh,
                            const float* __restrict__ bih,
                            const float* __restrict__ bhh,
                            uint4* __restrict__ Wpk, float* __restrict__ bias_sum) {
    int e = blockIdx.x * blockDim.x + threadIdx.x;  // 32768 elements
    if (e < G4) bias_sum[e] = bih[e] + bhh[e];
    int n = e >> 9, tid = e & 511;
    int j = tid >> 1, q = tid & 1;
    int g = (n < 48) ? (n >> 4) : 3;
    int m = (n < 48) ? (n & 15) : (n - 48);
    int r = g * F + j;
    int kp0 = q * 64 + m * 4;
    unsigned pk[4];
    #pragma unroll
    for (int i = 0; i < 4; ++i) {
        int k = 2 * (kp0 + i);
        float w0 = Wih[(size_t)r * F + k]     + Whh[(size_t)r * F + k];
        float w1 = Wih[(size_t)r * F + k + 1] + Whh[(size_t)r * F + k + 1];
        pk[i] = __builtin_bit_cast(unsigned, __floats2half2_rn(w0, w1));
    }
    Wpk[(size_t)n * 512 + tid] = make_uint4(pk[0], pk[1], pk[2], pk[3]);
}

// init = elu(x[0] @ Wi.T + bi) -> h0, c0 (fp32 in workspace), float4 loads
__global__ void init_kernel(const float* __restrict__ x,
                            const float* __restrict__ Wi,
                            const float* __restrict__ bi,
                            float* __restrict__ h, float* __restrict__ c) {
    __shared__ float4 xs4[L / 4];
    int b = blockIdx.x, j = threadIdx.x;
    if (j < L / 4) xs4[j] = ((const float4*)(x + (size_t)b * L))[j];
    __syncthreads();
    float acc = bi[j];
    const float4* wp = (const float4*)(Wi + (size_t)j * L);
    #pragma unroll 8
    for (int k = 0; k < L / 4; ++k) {
        float4 w = wp[k], xv = xs4[k];
        acc += w.x * xv.x + w.y * xv.y + w.z * xv.z + w.w * xv.w;
    }
    float v = acc > 0.0f ? acc : expm1f(acc);
    h[b * F + j] = v;
    c[b * F + j] = v;
}

// Step 0: gates = last_feat @ W_ih.T + h0 @ W_hh.T + bias (fp32 exact path).
__global__ void step0_kernel(const float* __restrict__ lf,
                             const float* __restrict__ Wih,
                             const float* __restrict__ Whh,
                             const float* __restrict__ bias_sum,
                             float* __restrict__ h, float* __restrict__ c,
                             float* __restrict__ out) {
    __shared__ float vecs[2 * F];            // [inp(256) ; h0(256)]
    __shared__ float partial[3][4][F];
    int b = blockIdx.x, tid = threadIdx.x;
    int j = tid & (F - 1), q = tid >> 8;
    if (q == 0) vecs[j] = lf[(size_t)b * F + j];
    else if (q == 1) vecs[F + j] = h[(size_t)b * F + j];
    __syncthreads();
    const float* mat = (q < 2) ? Wih : Whh;
    int ks = (q & 1) * 128;
    const float4* vp = (const float4*)(&vecs[(q >> 1) * F + ks]);
    float a[4] = {0.f, 0.f, 0.f, 0.f};
    #pragma unroll
    for (int g = 0; g < 4; ++g) {
        const float4* wp = (const float4*)(&mat[(size_t)(g * F + j) * F + ks]);
        float acc = 0.f;
        #pragma unroll 8
        for (int i = 0; i < 32; ++i) {
            float4 w = wp[i], v = vp[i];
            acc += w.x * v.x + w.y * v.y + w.z * v.z + w.w * v.w;
        }
        a[g] = acc;
    }
    if (q > 0) {
        #pragma unroll
        for (int g = 0; g < 4; ++g) partial[q - 1][g][j] = a[g];
    }
    __syncthreads();
    if (q == 0) {
        #pragma unroll
        for (int g = 0; g < 4; ++g) {
            for (int p = 0; p < 3; ++p) a[g] += partial[p][g][j];
            a[g] += bias_sum[g * F + j];
        }
        float c0v = c[(size_t)b * F + j];
        float c1v = sigf(a[1]) * c0v + sigf(a[0]) * tanhf_fast(a[2]);
        float h1v = sigf(a[3]) * tanhf_fast(c1v);
        h[(size_t)b * F + j] = h1v;
        c[(size_t)b * F + j] = c1v;
        out[(size_t)b * F + j] = h1v;  // t=0 row
    }
}

// Main recurrence v13: R3 (best measured, 790us) with COPY-FREE double-buffer.
// Diagnosis from R0-R10: wall = VALU 2810 cy/SIMD + ~900 exposure; v12 proved
// LDS had >=768 cy slack (cutting it regressed). The ~500 cy gap between
// measured VALU and the fdot2+tail budget is the rolling-prefetch mov churn:
// `hvA0=hvB0; woA0=woB0; ...` sits between sched_fence() calls, so the
// compiler cannot fold the loads into the consumed regs -> 16 v_mov/chunk
// x 8 chunks x 2 waves = ~512 cy/SIMD of copies. Fix: full unroll with TWO
// named register sets P/Q alternating by chunk parity -- chunk c computes
// from one set while c+1 loads directly into the other. No roll copies in
// source; fences stay. Liveness unchanged (8 uint4 in flight, as R3).
// Bonus: last chunk prefetches NEXT STEP's wo[0..1] (weights static across
// steps) so only the hv reads remain on the post-barrier critical path.
// hbuf bank-pad, deferred out-store, DPP reduce, single barrier: unchanged.
__launch_bounds__(512, 2)
__global__ void lstm_main(const uint4* __restrict__ Wpk,
                          const float* __restrict__ bias_sum,
                          const float* __restrict__ h_in,
                          const float* __restrict__ c_in,
                          float* __restrict__ out) {
    int b = blockIdx.x;
    int tid = threadIdx.x;
    int j = tid >> 1;
    int q = tid & 1;

    __shared__ uint4 lds_wo[16][512];   // gate-o weights, 128 KB
    __shared__ uint4 hbuf4[2][34];      // 2 buffers x (2 halves x 17 uint4, 16B pad)

    // One-time: gates i,f,g into registers (coalesced), gate o into LDS.
    uint4 wr[48];
    #pragma unroll
    for (int n = 0; n < 48; ++n) wr[n] = Wpk[(size_t)n * 512 + tid];
    #pragma unroll
    for (int m = 0; m < 16; ++m) lds_wo[m][tid] = Wpk[(size_t)(48 + m) * 512 + tid];

    float bias0 = bias_sum[0 * F + j];
    float bias1 = bias_sum[1 * F + j];
    float bias2 = bias_sum[2 * F + j];
    float bias3 = bias_sum[3 * F + j];
    float cj = c_in[(size_t)b * F + j];

    if (tid < F) {
        __half* hp = (__half*)&hbuf4[0][(tid >> 7) * 17];
        hp[tid & 127] = __float2half(h_in[(size_t)b * F + tid]);
    }
    __syncthreads();

    // steady state: woP carries chunk 0's wo pair across the barrier
    uint4 woP0 = lds_wo[0][tid], woP1 = lds_wo[1][tid];
    uint4 hvP0, hvP1, hvQ0, hvQ1, woQ0, woQ1;

    int cur = 0;
    float hprev = 0.f;  // deferred out-store value (q==1 path)
    for (int t = 1; t < S; ++t) {
        const uint4* hb = &hbuf4[cur][q * 17];
        hvP0 = hb[0];
        hvP1 = hb[1];
        // deferred store of previous step's h row: issued here, drained by
        // the end-of-step barrier ~a full step later -> hidden.
        if (q == 1 && t > 1) {
            __builtin_nontemporal_store(hprev, &out[((size_t)(t - 1) * B + b) * F + j]);
        }
        float a0 = 0.f, a1 = 0.f, a2 = 0.f, a3 = 0.f;

        // COMP: consume one register set for sub-chunks i0, i0+1.
#define COMP(hv0v, hv1v, wo0v, wo1v, i0)                                       \
        {                                                                      \
            uint4 w0 = wr[i0], w1 = wr[16 + (i0)], w2 = wr[32 + (i0)];         \
            a0 = fdot2u(w0.x, (hv0v).x, a0); a0 = fdot2u(w0.y, (hv0v).y, a0);  \
            a0 = fdot2u(w0.z, (hv0v).z, a0); a0 = fdot2u(w0.w, (hv0v).w, a0);  \
            a1 = fdot2u(w1.x, (hv0v).x, a1); a1 = fdot2u(w1.y, (hv0v).y, a1);  \
            a1 = fdot2u(w1.z, (hv0v).z, a1); a1 = fdot2u(w1.w, (hv0v).w, a1);  \
            a2 = fdot2u(w2.x, (hv0v).x, a2); a2 = fdot2u(w2.y, (hv0v).y, a2);  \
            a2 = fdot2u(w2.z, (hv0v).z, a2); a2 = fdot2u(w2.w, (hv0v).w, a2);  \
            a3 = fdot2u((wo0v).x, (hv0v).x, a3); a3 = fdot2u((wo0v).y, (hv0v).y, a3); \
            a3 = fdot2u((wo0v).z, (hv0v).z, a3); a3 = fdot2u((wo0v).w, (hv0v).w, a3); \
            uint4 w0b = wr[(i0) + 1], w1b = wr[17 + (i0)], w2b = wr[33 + (i0)]; \
            a0 = fdot2u(w0b.x, (hv1v).x, a0); a0 = fdot2u(w0b.y, (hv1v).y, a0); \
            a0 = fdot2u(w0b.z, (hv1v).z, a0); a0 = fdot2u(w0b.w, (hv1v).w, a0); \
            a1 = fdot2u(w1b.x, (hv1v).x, a1); a1 = fdot2u(w1b.y, (hv1v).y, a1); \
            a1 = fdot2u(w1b.z, (hv1v).z, a1); a1 = fdot2u(w1b.w, (hv1v).w, a1); \
            a2 = fdot2u(w2b.x, (hv1v).x, a2); a2 = fdot2u(w2b.y, (hv1v).y, a2); \
            a2 = fdot2u(w2b.z, (hv1v).z, a2); a2 = fdot2u(w2b.w, (hv1v).w, a2); \
            a3 = fdot2u((wo1v).x, (hv1v).x, a3); a3 = fdot2u((wo1v).y, (hv1v).y, a3); \
            a3 = fdot2u((wo1v).z, (hv1v).z, a3); a3 = fdot2u((wo1v).w, (hv1v).w, a3); \
        }
#define LOADQ(c)                                                               \
        hvQ0 = hb[2 * (c)]; hvQ1 = hb[2 * (c) + 1];                            \
        woQ0 = lds_wo[2 * (c)][tid]; woQ1 = lds_wo[2 * (c) + 1][tid];
#define LOADP(c)                                                               \
        hvP0 = hb[2 * (c)]; hvP1 = hb[2 * (c) + 1];                            \
        woP0 = lds_wo[2 * (c)][tid]; woP1 = lds_wo[2 * (c) + 1][tid];

        LOADQ(1) COMP(hvP0, hvP1, woP0, woP1, 0)  sched_fence();
        LOADP(2) COMP(hvQ0, hvQ1, woQ0, woQ1, 2)  sched_fence();
        LOADQ(3) COMP(hvP0, hvP1, woP0, woP1, 4)  sched_fence();
        LOADP(4) COMP(hvQ0, hvQ1, woQ0, woQ1, 6)  sched_fence();
        LOADQ(5) COMP(hvP0, hvP1, woP0, woP1, 8)  sched_fence();
        LOADP(6) COMP(hvQ0, hvQ1, woQ0, woQ1, 10) sched_fence();
        LOADQ(7) COMP(hvP0, hvP1, woP0, woP1, 12) sched_fence();
        // last chunk: prefetch NEXT STEP's wo chunk-0 pair into woP
        woP0 = lds_wo[0][tid]; woP1 = lds_wo[1][tid];
        COMP(hvQ0, hvQ1, woQ0, woQ1, 14)
        sched_fence();
#undef COMP
#undef LOADQ
#undef LOADP

        // sum the 2 k-halves (lane pairs); both lanes get full sums
        a0 = dpp_add<0xB1>(a0) + bias0;
        a1 = dpp_add<0xB1>(a1) + bias1;
        a2 = dpp_add<0xB1>(a2) + bias2;
        a3 = dpp_add<0xB1>(a3) + bias3;
        float c2 = sigf(a1) * cj + sigf(a0) * tanhf_fast(a2);
        float h2 = sigf(a3) * tanhf_fast(c2);
        cj = c2;
        if (q == 0) {
            __half* hp = (__half*)&hbuf4[cur ^ 1][(j >> 7) * 17];
            hp[j & 127] = __float2half(h2);
        }
        hprev = h2;
        __syncthreads();
        cur ^= 1;
    }
    if (q == 1) {
        __builtin_nontemporal_store(hprev, &out[((size_t)(S - 1) * B + b) * F + j]);
    }
}

extern "C" void kernel_launch(void* const* d_in, const int* in_sizes, int n_in,
                              void* d_out, int out_size, void* d_ws, size_t ws_size,
                              hipStream_t stream) {
    const float* x   = (const float*)d_in[0];
    const float* lf  = (const float*)d_in[1];
    const float* Wi  = (const float*)d_in[2];
    const float* bi  = (const float*)d_in[3];
    const float* Wih = (const float*)d_in[4];
    const float* Whh = (const float*)d_in[5];
    const float* bih = (const float*)d_in[6];
    const float* bhh = (const float*)d_in[7];
    // d_in[8], d_in[9] (Wo, bo): computed-and-discarded in the reference; unused.
    float* out = (float*)d_out;

    float* ws    = (float*)d_ws;
    float* h     = ws;               // 65536 floats
    float* c     = ws + 65536;       // 65536 floats
    float* bias  = ws + 131072;      // 1024 floats
    uint4* Wpk   = (uint4*)(ws + 132096);  // 64 chunks x 512 x 16B = 512 KB

    prep_kernel<<<128, 256, 0, stream>>>(Wih, Whh, bih, bhh, Wpk, bias);
    init_kernel<<<B, F, 0, stream>>>(x, Wi, bi, h, c);
    step0_kernel<<<B, 1024, 0, stream>>>(lf, Wih, Whh, bias, h, c, out);
    lstm_main<<<B, 512, 0, stream>>>(Wpk, bias, h, c, out);
}